// Round 3
// baseline (9649.323 us; speedup 1.0000x reference)
//
#include <hip/hip_runtime.h>
#include <stdint.h>

#define T_STEPS 512
#define BATCH   512
#define DIN     128
#define HID     256
#define NCLS    1000
#define NG      32            // batch groups (16 rows each)
#define NS      4             // hidden slices (64 u each)
#define GSTRIDE 268           // G row stride (floats): 268%32=12 -> 2-way max on spill
#define HPAR    131072        // shorts per HexP parity buffer

typedef unsigned int u32;
typedef unsigned long long u64;
typedef __attribute__((ext_vector_type(8))) short  short8;
typedef __attribute__((ext_vector_type(4))) float  f32x4;

#define AT_LD(p)    __hip_atomic_load((p),  __ATOMIC_RELAXED, __HIP_MEMORY_SCOPE_AGENT)
#define AT_LDA(p)   __hip_atomic_load((p),  __ATOMIC_ACQUIRE, __HIP_MEMORY_SCOPE_AGENT)
#define AT_ST(p,v)  __hip_atomic_store((p),(v),__ATOMIC_RELAXED, __HIP_MEMORY_SCOPE_AGENT)
#define AT_STR(p,v) __hip_atomic_store((p),(v),__ATOMIC_RELEASE, __HIP_MEMORY_SCOPE_AGENT)

__device__ __forceinline__ short f2bf(float f){
  u32 u = __float_as_uint(f);
  u32 r = (u + 0x7FFFu + ((u >> 16) & 1u)) >> 16;   // RNE
  return (short)r;
}
__device__ __forceinline__ short8 cvt8(f32x4 a, f32x4 b){
  short8 v;
  v[0]=f2bf(a[0]); v[1]=f2bf(a[1]); v[2]=f2bf(a[2]); v[3]=f2bf(a[3]);
  v[4]=f2bf(b[0]); v[5]=f2bf(b[1]); v[6]=f2bf(b[2]); v[7]=f2bf(b[3]);
  return v;
}

// ---------------------------------------------------------------------------
__global__ void init_ws(u32* p, int n){
  int i = blockIdx.x*256 + threadIdx.x;
  if (i < n) p[i] = 0;
}

// ---------------------------------------------------------------------------
// Pack W_ih (768x128) / W_hh (768x256) fp32 -> bf16 fragments:
// P[kb][j][e] = W[j][kb*8+e]. Lane(c,g) B-frag for (kt, col j) = P[kt*4+g][j][0..7].
// ---------------------------------------------------------------------------
__global__ __launch_bounds__(256) void pack_weights(
    const float* __restrict__ Wih, const float* __restrict__ Whh,
    short* __restrict__ PIH, short* __restrict__ PHH)
{
  int idx = blockIdx.x * 256 + threadIdx.x;   // 16*768 + 32*768 = 36864 groups
  if (idx >= 48*768) return;
  const float* src; short* dst;
  if (idx < 16*768){
    int kb = idx / 768, j = idx - kb*768;
    src = Wih + (size_t)j*DIN + kb*8;
    dst = PIH + (size_t)idx*8;
  } else {
    int i2 = idx - 16*768;
    int kb = i2 / 768, j = i2 - kb*768;
    src = Whh + (size_t)j*HID + kb*8;
    dst = PHH + (size_t)i2*8;
  }
  short8 v;
  #pragma unroll
  for (int e=0;e<8;e++) v[e] = f2bf(src[e]);
  *(short8*)dst = v;
}

// ---------------------------------------------------------------------------
// Persistent GRU scan, hidden-split 4-way.
// Grid 128 = 32 groups (16 batch rows) x 4 slices (64 hidden u). 256 thr.
// Weights register-resident (36 frags/lane). h exchanged through agent-scope
// global buffer HexP (parity double-buffered) + per-block counter flags.
// Race-freedom: step T writes parity T&1 only after peers' flags >= T, i.e.
// after peers finished their step-(T-1) reads of parity T&1 (h(T-2)).
// ---------------------------------------------------------------------------
__global__ __launch_bounds__(256, 1) void gru_scan(
    const float* __restrict__ x,    const float* __restrict__ b_ih,
    const float* __restrict__ b_hh, const float* __restrict__ mask,
    const short* __restrict__ PIH,  const short* __restrict__ PHH,
    short* __restrict__ HexP, u32* __restrict__ flags,
    float* __restrict__ HFIN)
{
  __shared__ float Gs[16*GSTRIDE];   // pre-activations: rows=batch, cols r|z|in|hn x64

  const int tid = threadIdx.x;
  const int grp = blockIdx.x & 31;
  const int sl  = blockIdx.x >> 5;         // stride-32 peers: same XCD if round-robin
  const int b0  = grp*16, u0 = sl*64;
  const int w   = tid>>6, l = tid&63, c = l&15, g4 = l>>4;

  // ---- one-time: weight fragments into registers (36 per lane) ----
  const int jr = u0 + w*16 + c, jz = jr+256, jn = jr+512;
  short8 wri[4], wzi[4], wni[4], wrh[8], wzh[8], wnh[8];
  #pragma unroll
  for (int kt=0;kt<4;kt++){
    size_t kb8 = (size_t)(kt*4+g4)*768;
    wri[kt] = *(const short8*)(PIH + (kb8 + jr)*8);
    wzi[kt] = *(const short8*)(PIH + (kb8 + jz)*8);
    wni[kt] = *(const short8*)(PIH + (kb8 + jn)*8);
  }
  #pragma unroll
  for (int kt=0;kt<8;kt++){
    size_t kb8 = (size_t)(kt*4+g4)*768;
    wrh[kt] = *(const short8*)(PHH + (kb8 + jr)*8);
    wzh[kt] = *(const short8*)(PHH + (kb8 + jz)*8);
    wnh[kt] = *(const short8*)(PHH + (kb8 + jn)*8);
  }

  // ---- gate-thread constants: thread owns (bb = tid>>4, u = u0 + (tid&15)*4 +0..3)
  const int bb = tid>>4, u4 = (tid&15)*4;
  f32x4 br4 = *(const f32x4*)(b_ih + u0+u4);
  { f32x4 q = *(const f32x4*)(b_hh + u0+u4);       br4 += q; }
  f32x4 bz4 = *(const f32x4*)(b_ih + 256+u0+u4);
  { f32x4 q = *(const f32x4*)(b_hh + 256+u0+u4);   bz4 += q; }
  f32x4 bi4 = *(const f32x4*)(b_ih + 512+u0+u4);
  f32x4 bh4 = *(const f32x4*)(b_hh + 512+u0+u4);

  const float* xlane = x + ((size_t)(b0+c)*T_STEPS)*DIN + g4*8;
  const float* mlane = mask + (size_t)(b0+bb)*HID + u0 + u4;
  const int hlaneoff  = grp*4096 + g4*128 + c*8;                 // shorts
  const int kbw       = (u0+u4)>>3;
  const int hstoreoff = grp*4096 + kbw*128 + bb*8 + (u4&7);      // shorts, 8B-aligned
  u32* const myflag = flags + grp*NS + sl;
  const u32* fp0 = flags + grp*NS + ((sl+1)&3);
  const u32* fp1 = flags + grp*NS + ((sl+2)&3);
  const u32* fp2 = flags + grp*NS + ((sl+3)&3);
  const int gbase = (g4*4)*GSTRIDE + w*16 + c;   // spill base (row g4*4, col sec*64+w*16+c)
  const int grow  = bb*GSTRIDE;

  float hreg[4] = {0.f,0.f,0.f,0.f};

  // ---- prologue: x(0), mask(0) ----
  short8 xfA[4], xfB[4];
  f32x4  mkA, mkB;
  #pragma unroll
  for (int kt=0;kt<4;kt++){
    const float* bp = xlane + kt*32;
    xfA[kt] = cvt8(*(const f32x4*)bp, *(const f32x4*)(bp+4));
  }
  mkA = *(const f32x4*)(mlane);
  __syncthreads();

#define STEP(T,PAR,XC,XN,MC,MN) {                                              \
  const int tn = (T)+1;                                                        \
  /* 1. prefetch x(t+1), mask(t+1) — in flight during the spin */              \
  f32x4 xr[8];                                                                 \
  if (tn < T_STEPS){                                                           \
    _Pragma("unroll") for (int kt=0;kt<4;kt++){                                \
      const float* bp = xlane + (size_t)tn*DIN + kt*32;                        \
      xr[2*kt]   = *(const f32x4*)(bp);                                        \
      xr[2*kt+1] = *(const f32x4*)(bp+4);                                      \
    }                                                                          \
    MN = *(const f32x4*)(mlane + (size_t)tn*(BATCH*HID));                      \
  }                                                                            \
  /* 2. spin: peers finished step T-1 (instant in steady state) */             \
  { const u32 need = (u32)(T);                                                 \
    while (AT_LDA(fp0) < need) __builtin_amdgcn_s_sleep(1);                    \
    while (AT_LDA(fp1) < need) __builtin_amdgcn_s_sleep(1);                    \
    while (AT_LDA(fp2) < need) __builtin_amdgcn_s_sleep(1); }                  \
  /* 3. issue peer-h fragment loads (parity PAR^1) */                          \
  short8 hf[8];                                                                \
  { const short* hb = HexP + (size_t)((PAR)^1)*HPAR + hlaneoff;                \
    _Pragma("unroll") for (int kt=0;kt<8;kt++){                                \
      union { u64 q[2]; short8 v; } uq;                                        \
      uq.q[0] = AT_LD((const u64*)(hb + kt*512));                              \
      uq.q[1] = AT_LD((const u64*)(hb + kt*512 + 4));                          \
      hf[kt] = uq.v; } }                                                       \
  /* 4. x-part MFMAs (cover h-load latency) */                                 \
  f32x4 ar={0.f,0.f,0.f,0.f}, az=ar, ain=ar, ahn=ar;                           \
  _Pragma("unroll") for (int kt=0;kt<4;kt++){                                  \
    ar  = __builtin_amdgcn_mfma_f32_16x16x32_bf16(XC[kt], wri[kt], ar, 0,0,0); \
    az  = __builtin_amdgcn_mfma_f32_16x16x32_bf16(XC[kt], wzi[kt], az, 0,0,0); \
    ain = __builtin_amdgcn_mfma_f32_16x16x32_bf16(XC[kt], wni[kt], ain,0,0,0); \
  }                                                                            \
  /* 5. h-part MFMAs */                                                        \
  _Pragma("unroll") for (int kt=0;kt<8;kt++){                                  \
    ar  = __builtin_amdgcn_mfma_f32_16x16x32_bf16(hf[kt], wrh[kt], ar, 0,0,0); \
    az  = __builtin_amdgcn_mfma_f32_16x16x32_bf16(hf[kt], wzh[kt], az, 0,0,0); \
    ahn = __builtin_amdgcn_mfma_f32_16x16x32_bf16(hf[kt], wnh[kt], ahn,0,0,0); \
  }                                                                            \
  /* 6. spill pre-activations (C/D: col=c, row=g4*4+i) */                      \
  _Pragma("unroll") for (int i=0;i<4;i++){                                     \
    Gs[gbase + i*GSTRIDE      ] = ar[i];                                       \
    Gs[gbase + i*GSTRIDE +  64] = az[i];                                       \
    Gs[gbase + i*GSTRIDE + 128] = ain[i];                                      \
    Gs[gbase + i*GSTRIDE + 192] = ahn[i]; }                                    \
  __syncthreads();                                                             \
  /* 7. gate math */                                                           \
  { f32x4 gr = *(const f32x4*)&Gs[grow       + u4];                            \
    f32x4 gz = *(const f32x4*)&Gs[grow +  64 + u4];                            \
    f32x4 gi = *(const f32x4*)&Gs[grow + 128 + u4];                            \
    f32x4 gh = *(const f32x4*)&Gs[grow + 192 + u4];                            \
    _Pragma("unroll") for (int e=0;e<4;e++){                                   \
      float r_ = 1.f/(1.f + __expf(-(gr[e]+br4[e])));                          \
      float z_ = 1.f/(1.f + __expf(-(gz[e]+bz4[e])));                          \
      float e2 = __expf(2.f*(gi[e]+bi4[e] + r_*(gh[e]+bh4[e])));               \
      float n_ = 1.f - 2.f/(e2 + 1.f);                                         \
      hreg[e] = ((1.f - z_)*n_ + z_*hreg[e]) * MC[e];                          \
    }                                                                          \
    u32 lo_ = ((u32)(unsigned short)f2bf(hreg[0])) |                           \
              (((u32)(unsigned short)f2bf(hreg[1]))<<16);                      \
    u32 hi_ = ((u32)(unsigned short)f2bf(hreg[2])) |                           \
              (((u32)(unsigned short)f2bf(hreg[3]))<<16);                      \
    u64 pk = ((u64)hi_<<32) | (u64)lo_;                                        \
    AT_ST((u64*)(HexP + (size_t)(PAR)*HPAR + hstoreoff), pk);                  \
  }                                                                            \
  /* 8. convert next x frags */                                                \
  if (tn < T_STEPS){                                                           \
    _Pragma("unroll") for (int kt=0;kt<4;kt++)                                 \
      XN[kt] = cvt8(xr[2*kt], xr[2*kt+1]);                                     \
  }                                                                            \
  /* 9. publish: all waves drain stores -> barrier -> flag */                  \
  asm volatile("s_waitcnt vmcnt(0)" ::: "memory");                             \
  __syncthreads();                                                             \
  if (tid == 0) AT_STR(myflag, (u32)((T)+1));                                  \
}

  for (int tt=0; tt<T_STEPS; tt+=2){
    STEP(tt,   0, xfA, xfB, mkA, mkB);
    STEP(tt+1, 1, xfB, xfA, mkB, mkA);
  }
#undef STEP

  // ---- epilogue: final h (fp32 master) ----
  f32x4 hv; hv[0]=hreg[0]; hv[1]=hreg[1]; hv[2]=hreg[2]; hv[3]=hreg[3];
  *(f32x4*)&HFIN[(size_t)(b0+bb)*HID + u0 + u4] = hv;
}

// ---------------------------------------------------------------------------
// out = h @ W_out^T + b_out   (512x256 @ 256x1000), fp32 vector.
// ---------------------------------------------------------------------------
__global__ __launch_bounds__(256) void out_gemm(
    const float* __restrict__ Hf, const float* __restrict__ Wout,
    const float* __restrict__ bout, float* __restrict__ out)
{
  __shared__ float hl[16*256];
  const int bb0 = (blockIdx.x >> 4) * 16;
  const int cc0 = (blockIdx.x & 15) * 64;
  for (int i=threadIdx.x; i<16*256; i+=256) hl[i] = Hf[(size_t)bb0*256 + i];
  __syncthreads();
  const int cc = cc0 + (threadIdx.x & 63);
  const int br = threadIdx.x >> 6;
  if (cc >= NCLS) return;
  const f32x4* wr = (const f32x4*)(Wout + (size_t)cc*HID);
  float a0=0.f, a1=0.f, a2=0.f, a3=0.f;
  #pragma unroll 8
  for (int k4=0;k4<64;k4++){
    f32x4 wv = wr[k4];
    #pragma unroll
    for (int e=0;e<4;e++){
      float we = wv[e]; int k = k4*4+e;
      a0 += hl[(br   )*256+k]*we;
      a1 += hl[(br+ 4)*256+k]*we;
      a2 += hl[(br+ 8)*256+k]*we;
      a3 += hl[(br+12)*256+k]*we;
    }
  }
  float bo = bout[cc];
  out[(size_t)(bb0+br   )*NCLS + cc] = a0 + bo;
  out[(size_t)(bb0+br+ 4)*NCLS + cc] = a1 + bo;
  out[(size_t)(bb0+br+ 8)*NCLS + cc] = a2 + bo;
  out[(size_t)(bb0+br+12)*NCLS + cc] = a3 + bo;
}

// ---------------------------------------------------------------------------
extern "C" void kernel_launch(void* const* d_in, const int* in_sizes, int n_in,
                              void* d_out, int out_size, void* d_ws, size_t ws_size,
                              hipStream_t stream) {
  const float* x     = (const float*)d_in[0];
  const float* W_ih  = (const float*)d_in[1];
  const float* W_hh  = (const float*)d_in[2];
  const float* b_ih  = (const float*)d_in[3];
  const float* b_hh  = (const float*)d_in[4];
  const float* W_out = (const float*)d_in[5];
  const float* b_out = (const float*)d_in[6];
  const float* dmask = (const float*)d_in[7];

  // ws: PIH 196608B | PHH 393216B | HFIN 524288B | HexP 524288B | flags 512B
  short* PIH  = (short*)d_ws;
  short* PHH  = (short*)((char*)d_ws + 196608);
  float* HFIN = (float*)((char*)d_ws + 589824);
  short* HexP = (short*)((char*)d_ws + 1114112);
  u32*   flags= (u32*)  ((char*)d_ws + 1638400);

  init_ws<<<513, 256, 0, stream>>>((u32*)HexP, 131200);   // zero HexP + flags
  pack_weights<<<144, 256, 0, stream>>>(W_ih, W_hh, PIH, PHH);
  gru_scan<<<NG*NS, 256, 0, stream>>>(x, b_ih, b_hh, dmask, PIH, PHH,
                                      HexP, flags, HFIN);
  out_gemm<<<512, 256, 0, stream>>>(HFIN, W_out, b_out, (float*)d_out);
}

// Round 5
// 1787.381 us; speedup vs baseline: 5.3986x; 5.3986x over previous
//
#include <hip/hip_runtime.h>
#include <stdint.h>

#define T_STEPS 512
#define BATCH   512
#define DIN     128
#define HID     256
#define NCLS    1000

typedef unsigned int u32;
typedef unsigned long long u64;
typedef __attribute__((ext_vector_type(8))) short  short8;
typedef __attribute__((ext_vector_type(4))) short  short4v;
typedef __attribute__((ext_vector_type(4))) float  f32x4;

__device__ __forceinline__ short f2bf(float f){
  u32 u = __float_as_uint(f);
  u32 r = (u + 0x7FFFu + ((u >> 16) & 1u)) >> 16;   // RNE
  return (short)r;
}
__device__ __forceinline__ float bf2f(unsigned short s){
  return __uint_as_float(((u32)s) << 16);
}
__device__ __forceinline__ short8 cvt8(f32x4 a, f32x4 b){
  short8 v;
  v[0]=f2bf(a[0]); v[1]=f2bf(a[1]); v[2]=f2bf(a[2]); v[3]=f2bf(a[3]);
  v[4]=f2bf(b[0]); v[5]=f2bf(b[1]); v[6]=f2bf(b[2]); v[7]=f2bf(b[3]);
  return v;
}
// async global->LDS, 16B per lane; lds dest = wave-uniform base + lane*16 (HW)
__device__ __forceinline__ void gload_lds16(const void* g, void* l){
  __builtin_amdgcn_global_load_lds(
      (const __attribute__((address_space(1))) unsigned int*)g,
      (__attribute__((address_space(3))) unsigned int*)l, 16, 0, 0);
}

// ---------------------------------------------------------------------------
// Pack W_ih (768x128) / W_hh (768x256) fp32 -> bf16 frags P[kb][j][0..7],
// frag(kt,g4,j) = P[kt*4+g4][j]  (validated layout: R1/R3 passed).
// ---------------------------------------------------------------------------
__global__ __launch_bounds__(256) void pack_weights(
    const float* __restrict__ Wih, const float* __restrict__ Whh,
    short* __restrict__ PIH, short* __restrict__ PHH)
{
  int idx = blockIdx.x * 256 + threadIdx.x;   // 16*768 + 32*768
  if (idx >= 48*768) return;
  const float* src; short* dst;
  if (idx < 16*768){
    int kb = idx / 768, j = idx - kb*768;
    src = Wih + (size_t)j*DIN + kb*8;
    dst = PIH + (size_t)idx*8;
  } else {
    int i2 = idx - 16*768;
    int kb = i2 / 768, j = i2 - kb*768;
    src = Whh + (size_t)j*HID + kb*8;
    dst = PHH + (size_t)i2*8;
  }
  short8 v;
  #pragma unroll
  for (int e=0;e<8;e++) v[e] = f2bf(src[e]);
  *(short8*)dst = v;
}

// ---------------------------------------------------------------------------
// drop_mask fp32 (T,B,H) -> bitmask MB[t][gb(=b>>3)][r(=b&7)][32B], 1 bit/u.
// ---------------------------------------------------------------------------
__global__ __launch_bounds__(256) void mask_bits(
    const float* __restrict__ mask, unsigned char* __restrict__ MBo)
{
  int idx = blockIdx.x*256 + threadIdx.x;      // 512*512*32 = 8388608
  int t = idx >> 14, rem = idx & 16383, bb = rem >> 5, ub = rem & 31;
  const float* mp = mask + ((size_t)t*BATCH + bb)*HID + ub*8;
  u32 byte = 0;
  #pragma unroll
  for (int e=0;e<8;e++) byte |= (mp[e] > 0.5f ? 1u : 0u) << e;
  MBo[((size_t)t*64 + (bb>>3))*256 + (bb&7)*32 + ub] = (unsigned char)byte;
}

// ---------------------------------------------------------------------------
// gi = x @ W_ih^T + b_ih (+ b_hh for r,z sections).  M=(b,t)=262144, N=768,
// K=128.  Output per (gb,tp): 16 m-rows (m = tt*8 + r, t = tp*2+tt, b=gb*8+r):
//   r,z -> GIbf[gb][tp][m][j<512] bf16 ; n -> GIn[gb][tp][m][j-512] fp32.
// Block = (gb, tc): 4 tpairs x 16 m x 768, 512 thr, 8 waves (wave = 6 n-tiles).
// ---------------------------------------------------------------------------
__global__ __launch_bounds__(512, 1) void gi_gemm(
    const float* __restrict__ x, const float* __restrict__ b_ih,
    const float* __restrict__ b_hh, const short* __restrict__ PIH,
    short* __restrict__ GIbf, float* __restrict__ GIn)
{
  __shared__ __align__(16) short XT[64*136];   // A-tile bf16, stride 136
  const int tid = threadIdx.x;
  const int gb  = blockIdx.x >> 6;
  const int tc  = blockIdx.x & 63;
  const int tp0 = tc*4;
  const int w = tid>>6, l = tid&63, c = l&15, g4 = l>>4;

  // B-fragments (held across block) + folded bias
  short8 bfr[6][4]; float bj[6];
  #pragma unroll
  for (int q=0;q<6;q++){
    const int j = (w*6+q)*16 + c;
    #pragma unroll
    for (int kt=0;kt<4;kt++)
      bfr[q][kt] = *(const short8*)(PIH + ((size_t)(kt*4+g4)*768 + j)*8);
    bj[q] = b_ih[j] + (j < 512 ? b_hh[j] : 0.f);
  }

  // stage A: 64 rows x 128 k (fp32 -> bf16)
  {
    const int row = tid>>3, cc = (tid&7)*16;
    const int r = row&7, tpl = row>>4, tt = (row>>3)&1;
    const int bb = gb*8 + r;
    const int t  = (tp0+tpl)*2 + tt;
    const float* src = x + ((size_t)bb*T_STEPS + t)*DIN + cc;
    f32x4 a0 = *(const f32x4*)src,     a1 = *(const f32x4*)(src+4);
    f32x4 a2 = *(const f32x4*)(src+8), a3 = *(const f32x4*)(src+12);
    *(short8*)&XT[row*136 + cc]     = cvt8(a0,a1);
    *(short8*)&XT[row*136 + cc + 8] = cvt8(a2,a3);
  }
  __syncthreads();

  const f32x4 z4 = {0.f,0.f,0.f,0.f};
  #pragma unroll
  for (int mt=0; mt<4; ++mt){
    f32x4 acc[6];
    #pragma unroll
    for (int q=0;q<6;q++) acc[q] = z4;
    #pragma unroll
    for (int kt=0;kt<4;kt++){
      short8 af = *(const short8*)&XT[(mt*16+c)*136 + kt*32 + g4*8];
      #pragma unroll
      for (int q=0;q<6;q++)
        acc[q] = __builtin_amdgcn_mfma_f32_16x16x32_bf16(af, bfr[q][kt], acc[q], 0,0,0);
    }
    const int tp = tp0 + mt;
    const size_t base16 = ((size_t)gb*256 + tp)*16;
    #pragma unroll
    for (int q=0;q<6;q++){
      const int j = (w*6+q)*16 + c;
      if (j < 512){
        #pragma unroll
        for (int i=0;i<4;i++)
          GIbf[(base16 + g4*4+i)*512 + j] = f2bf(acc[q][i] + bj[q]);
      } else {
        #pragma unroll
        for (int i=0;i<4;i++)
          GIn[(base16 + g4*4+i)*256 + (j-512)] = acc[q][i] + bj[q];
      }
    }
  }
}

// ---------------------------------------------------------------------------
// Persistent scan: 64 blocks x 8 batch rows, 512 thr (8 waves).
// W_hh register-resident: wave w owns n-tiles w*6..w*6+5 (48 frags/lane).
// Per step: MFMA gh -> spill Gs -> raw barrier (lgkm only) -> gates -> h to
// Ah -> __syncthreads (single vmcnt drain; gi(t+1) stage stays in flight
// across the raw barrier).  No cross-block traffic.
// ---------------------------------------------------------------------------
__global__ __launch_bounds__(512, 1) void gru_scan(
    const float* __restrict__ b_hh, const unsigned char* __restrict__ MB,
    const short* __restrict__ PHH, const short* __restrict__ GIbf,
    const float* __restrict__ GIn, float* __restrict__ HFIN)
{
  __shared__ __align__(16) short Ah[16*264];     // h bf16 A-tile (rows 8..15 zero)
  __shared__ __align__(16) float Gs[8*776];      // gh spill: [b][j<768]
  __shared__ __align__(16) short GiRZ[2][8*512]; // gi r,z bf16, dbuf
  __shared__ __align__(16) float GiN [2][8*256]; // gi n fp32, dbuf

  const int tid = threadIdx.x;
  const int gb  = blockIdx.x;
  const int w = tid>>6, l = tid&63, c = l&15, g4 = l>>4;

  // ---- W_hh fragments -> registers (once) ----
  short8 whf[6][8];
  #pragma unroll
  for (int q=0;q<6;q++){
    const int j = (w*6+q)*16 + c;
    #pragma unroll
    for (int kt=0;kt<8;kt++)
      whf[q][kt] = *(const short8*)(PHH + ((size_t)(kt*4+g4)*768 + j)*8);
  }

  // ---- gate-thread constants: b = wave, u4 = lane*4 ----
  const int b  = tid>>6;
  const int u4 = (tid&63)*4;
  const f32x4 bhn4 = *(const f32x4*)(b_hh + 512 + u4);
  const int mboff = b*32 + ((tid&63)>>1);
  const int mshift = ((tid&63)&1) << 2;

  for (int i=tid; i<16*264; i+=512) Ah[i] = 0;

  // per-(gb,t) gi slices are contiguous 8192 B in each array
  const char* srz = (const char*)GIbf + (size_t)gb*256*16*512*2;
  const char* sn  = (const char*)GIn  + (size_t)gb*256*16*256*4;

  // stage t=0 into buf 0
  {
    gload_lds16(srz + (size_t)0*8192 + w*1024 + l*16, (char*)&GiRZ[0][w*512]);
    gload_lds16(sn  + (size_t)0*8192 + w*1024 + l*16, (char*)&GiN [0][w*256]);
  }
  u32 mbcur = MB[(size_t)gb*256 + mboff];
  float hreg[4] = {0.f,0.f,0.f,0.f};
  asm volatile("s_waitcnt vmcnt(0)" ::: "memory");
  __syncthreads();

  const int ar_off = c*264;
  const f32x4 z4 = {0.f,0.f,0.f,0.f};

  for (int t=0; t<T_STEPS; ++t){
    const int buf = t & 1;
    // ---- issue next-step staging (drains only at step-end sync) ----
    u32 mbnext = 0;
    if (t < T_STEPS-1){
      gload_lds16(srz + (size_t)(t+1)*8192 + w*1024 + l*16, (char*)&GiRZ[buf^1][w*512]);
      gload_lds16(sn  + (size_t)(t+1)*8192 + w*1024 + l*16, (char*)&GiN [buf^1][w*256]);
      mbnext = MB[((size_t)(t+1)*64 + gb)*256 + mboff];
    }
    // ---- gh = h @ W_hh^T : 48 MFMA / wave ----
    f32x4 acc[6];
    #pragma unroll
    for (int q=0;q<6;q++) acc[q] = z4;
    #pragma unroll
    for (int kt=0;kt<8;kt++){
      short8 af = *(const short8*)&Ah[ar_off + kt*32 + g4*8];
      #pragma unroll
      for (int q=0;q<6;q++)
        acc[q] = __builtin_amdgcn_mfma_f32_16x16x32_bf16(af, whf[q][kt], acc[q], 0,0,0);
    }
    // ---- spill rows 0..7 (C/D: col=c, row=g4*4+i) ----
    if (g4 < 2){
      #pragma unroll
      for (int q=0;q<6;q++){
        const int j = (w*6+q)*16 + c;
        #pragma unroll
        for (int i=0;i<4;i++)
          Gs[(g4*4+i)*776 + j] = acc[q][i];
      }
    }
    // ---- raw barrier: LDS complete, VMEM stays in flight ----
    asm volatile("s_waitcnt lgkmcnt(0)" ::: "memory");
    __builtin_amdgcn_sched_barrier(0);
    __builtin_amdgcn_s_barrier();
    __builtin_amdgcn_sched_barrier(0);
    // ---- gates ----
    {
      f32x4 gr = *(const f32x4*)&Gs[b*776       + u4];
      f32x4 gz = *(const f32x4*)&Gs[b*776 + 256 + u4];
      f32x4 gn = *(const f32x4*)&Gs[b*776 + 512 + u4];
      short4v sr = *(const short4v*)&GiRZ[buf][b*512       + u4];
      short4v sz = *(const short4v*)&GiRZ[buf][b*512 + 256 + u4];
      f32x4 gin = *(const f32x4*)&GiN[buf][b*256 + u4];
      short hb0,hb1,hb2,hb3;
      #pragma unroll
      for (int e=0;e<4;e++){
        float r_ = 1.f/(1.f + __expf(-(gr[e] + bf2f((unsigned short)sr[e]))));
        float z_ = 1.f/(1.f + __expf(-(gz[e] + bf2f((unsigned short)sz[e]))));
        float e2 = __expf(2.f*(gin[e] + r_*(gn[e] + bhn4[e])));
        float n_ = 1.f - 2.f/(e2 + 1.f);
        float mv = ((mbcur >> (mshift + e)) & 1u) ? 1.3333334f : 0.f;
        hreg[e] = ((1.f - z_)*n_ + z_*hreg[e]) * mv;
      }
      hb0=f2bf(hreg[0]); hb1=f2bf(hreg[1]); hb2=f2bf(hreg[2]); hb3=f2bf(hreg[3]);
      short4v hv; hv[0]=hb0; hv[1]=hb1; hv[2]=hb2; hv[3]=hb3;
      *(short4v*)&Ah[b*264 + u4] = hv;
    }
    mbcur = mbnext;
    // ---- single drain point: stage(t+1) complete + Ah visible ----
    asm volatile("s_waitcnt vmcnt(0)" ::: "memory");
    __syncthreads();
  }

  f32x4 hv; hv[0]=hreg[0]; hv[1]=hreg[1]; hv[2]=hreg[2]; hv[3]=hreg[3];
  *(f32x4*)&HFIN[((size_t)(gb*8 + b))*HID + u4] = hv;
}

// ---------------------------------------------------------------------------
// out = h @ W_out^T + b_out   (512x256 @ 256x1000), fp32 vector.
// ---------------------------------------------------------------------------
__global__ __launch_bounds__(256) void out_gemm(
    const float* __restrict__ Hf, const float* __restrict__ Wout,
    const float* __restrict__ bout, float* __restrict__ out)
{
  __shared__ __align__(16) float hl[16*256];
  const int bb0 = (blockIdx.x >> 4) * 16;
  const int cc0 = (blockIdx.x & 15) * 64;
  for (int i=threadIdx.x; i<16*256; i+=256) hl[i] = Hf[(size_t)bb0*HID + i];
  __syncthreads();
  const int cc = cc0 + (threadIdx.x & 63);
  const int br = threadIdx.x >> 6;
  if (cc >= NCLS) return;
  const f32x4* wr = (const f32x4*)(Wout + (size_t)cc*HID);
  float a0=0.f, a1=0.f, a2=0.f, a3=0.f;
  #pragma unroll 8
  for (int k4=0;k4<64;k4++){
    f32x4 wv = wr[k4];
    #pragma unroll
    for (int e=0;e<4;e++){
      float we = wv[e]; int k = k4*4+e;
      a0 += hl[(br   )*256+k]*we;
      a1 += hl[(br+ 4)*256+k]*we;
      a2 += hl[(br+ 8)*256+k]*we;
      a3 += hl[(br+12)*256+k]*we;
    }
  }
  float bo = bout[cc];
  out[(size_t)(bb0+br   )*NCLS + cc] = a0 + bo;
  out[(size_t)(bb0+br+ 4)*NCLS + cc] = a1 + bo;
  out[(size_t)(bb0+br+ 8)*NCLS + cc] = a2 + bo;
  out[(size_t)(bb0+br+12)*NCLS + cc] = a3 + bo;
}

// ---------------------------------------------------------------------------
extern "C" void kernel_launch(void* const* d_in, const int* in_sizes, int n_in,
                              void* d_out, int out_size, void* d_ws, size_t ws_size,
                              hipStream_t stream) {
  const float* x     = (const float*)d_in[0];
  const float* W_ih  = (const float*)d_in[1];
  const float* W_hh  = (const float*)d_in[2];
  const float* b_ih  = (const float*)d_in[3];
  const float* b_hh  = (const float*)d_in[4];
  const float* W_out = (const float*)d_in[5];
  const float* b_out = (const float*)d_in[6];
  const float* dmask = (const float*)d_in[7];

  // ws layout (bytes):
  //   PIH   0         .. 196608
  //   PHH   196608    .. 589824
  //   HFIN  589824    .. 1114112
  //   MB    1114112   .. 9502720
  //   GIbf  9502720   .. 277938176   (64*256*16*512 bf16)
  //   GIn   277938176 .. 546373632   (64*256*16*256 fp32)
  if (ws_size < 546373632ull) return;   // clean fail if scratch too small
  short* PIH  = (short*)d_ws;
  short* PHH  = (short*)((char*)d_ws + 196608);
  float* HFIN = (float*)((char*)d_ws + 589824);
  unsigned char* MBp = (unsigned char*)d_ws + 1114112;
  short* GIbf = (short*)((char*)d_ws + 9502720);
  float* GIn  = (float*)((char*)d_ws + 277938176);

  pack_weights<<<144, 256, 0, stream>>>(W_ih, W_hh, PIH, PHH);
  mask_bits<<<32768, 256, 0, stream>>>(dmask, MBp);
  gi_gemm<<<4096, 512, 0, stream>>>(x, b_ih, b_hh, PIH, GIbf, GIn);
  gru_scan<<<64, 512, 0, stream>>>(b_hh, MBp, PHH, GIbf, GIn, HFIN);
  out_gemm<<<512, 256, 0, stream>>>(HFIN, W_out, b_out, (float*)d_out);
}